// Round 4
// baseline (139.951 us; speedup 1.0000x reference)
//
#include <hip/hip_runtime.h>
#include <hip/hip_cooperative_groups.h>

namespace cg = cooperative_groups;

#define BATCH 64
#define CLSN 80
#define BBOXN 2
#define HWN (56 * 56)
#define NCELLS (BATCH * HWN)   // 200704
#define NTHR 256
#define NBLK (NCELLS / NTHR)   // 784, exact; co-resident (<= 2048 blocks)

// ws layout: float4 partials[NBLK]  {neg, cls, resp, off}

__global__ void yolo_onepass_kernel(const float* __restrict__ pred_cls,
                                    const float* __restrict__ pred_resp,
                                    const float* __restrict__ pred_box,
                                    const float* __restrict__ label_cls,
                                    const float* __restrict__ label_resp,
                                    const float* __restrict__ label_box,
                                    float4* __restrict__ partials,
                                    float* __restrict__ out) {
    const int tid = threadIdx.x;
    const int i = blockIdx.x * NTHR + tid;          // grid covers NCELLS exactly
    const int b = i / HWN;
    const int yx = i - b * HWN;
    const int rbase = b * (BBOXN * HWN) + yx;

    // coalesced: consecutive threads -> consecutive yx
    const float l0 = label_resp[rbase];
    const float l1 = label_resp[rbase + HWN];
    const float p0 = pred_resp[rbase];
    const float p1 = pred_resp[rbase + HWN];

    float negAcc = 0.0f, clsAcc = 0.0f, respAcc = 0.0f, offAcc = 0.0f;
    if (l0 < 1.0f) { float d = p0 - l0; negAcc += d * d; }
    if (l1 < 1.0f) { float d = p1 - l1; negAcc += d * d; }

    const bool sel = (l0 + l1) >= 0.5f;

    // ---- issue the scattered box loads EARLY; consume after the cls loop ----
    float t[8], p[8];
    if (sel) {
        const int bbase = b * (BBOXN * 4) * HWN + yx;
        #pragma unroll
        for (int k = 0; k < 8; ++k) {
            t[k] = label_box[bbase + k * HWN];
            p[k] = pred_box[bbase + k * HWN];
        }
    }

    // ---- classification loss: wave-cooperative over selected lanes ----
    const int lane = tid & 63;
    unsigned long long mask = __ballot(sel);
    while (mask) {
        const int srcLane = (int)__builtin_ctzll(mask);
        mask &= mask - 1;
        const int ci = __shfl(i, srcLane, 64);
        const int cb = ci / HWN;
        const int cyx = ci - cb * HWN;
        const int cbase = cb * (CLSN * HWN) + cyx;
        {
            const int ofs = cbase + lane * HWN;
            float d = pred_cls[ofs] - label_cls[ofs];
            clsAcc += d * d;
        }
        if (lane < CLSN - 64) {
            const int ofs = cbase + (64 + lane) * HWN;
            float d = pred_cls[ofs] - label_cls[ofs];
            clsAcc += d * d;
        }
    }

    // ---- box / response loss: consume the early-issued loads ----
    if (sel) {
        float iou[2];
        #pragma unroll
        for (int bx = 0; bx < 2; ++bx) {
            float tx1 = t[bx * 4 + 0] - t[bx * 4 + 2] * 0.5f;
            float ty1 = t[bx * 4 + 1] - t[bx * 4 + 3] * 0.5f;
            float tx2 = tx1 + t[bx * 4 + 2];
            float ty2 = ty1 + t[bx * 4 + 3];
            float px1 = p[bx * 4 + 0] - p[bx * 4 + 2] * 0.5f;
            float py1 = p[bx * 4 + 1] - p[bx * 4 + 3] * 0.5f;
            float px2 = px1 + p[bx * 4 + 2];
            float py2 = py1 + p[bx * 4 + 3];
            float ltx = fmaxf(tx1, px1), lty = fmaxf(ty1, py1);
            float rbx = fminf(tx2, px2), rby = fminf(ty2, py2);
            float w_ = fmaxf(rbx - ltx, 0.0f), h_ = fmaxf(rby - lty, 0.0f);
            float inter = w_ * h_;
            float a1 = (tx2 - tx1) * (ty2 - ty1);
            float a2 = (px2 - px1) * (py2 - py1);
            iou[bx] = inter / (a1 + a2 - inter + 0.0001f);
        }
        const int best = (iou[1] > iou[0]) ? 1 : 0;   // argmax, ties -> 0
        const float pr = best ? p1 : p0;              // pred_resp already loaded
        const float dr = pr - iou[best];
        respAcc = dr * dr;
        #pragma unroll
        for (int k = 0; k < 4; ++k) {
            float d2 = p[best * 4 + k] - t[best * 4 + k];
            offAcc += d2 * d2;
        }
    }

    // ---- block reduction, one float4 store per block ----
    #pragma unroll
    for (int o = 32; o > 0; o >>= 1) {
        negAcc  += __shfl_down(negAcc,  o, 64);
        clsAcc  += __shfl_down(clsAcc,  o, 64);
        respAcc += __shfl_down(respAcc, o, 64);
        offAcc  += __shfl_down(offAcc,  o, 64);
    }
    __shared__ float4 s[NTHR / 64];
    if ((tid & 63) == 0) s[tid >> 6] = make_float4(negAcc, clsAcc, respAcc, offAcc);
    __syncthreads();
    if (tid == 0) {
        float4 tt = s[0];
        #pragma unroll
        for (int w = 1; w < NTHR / 64; ++w) {
            tt.x += s[w].x; tt.y += s[w].y; tt.z += s[w].z; tt.w += s[w].w;
        }
        partials[blockIdx.x] = tt;
        __threadfence();   // device-scope visibility across XCDs before grid sync
    }

    cg::this_grid().sync();

    // ---- finalize: block 0 reduces the 784 partials ----
    if (blockIdx.x == 0) {
        double neg = 0.0, cls = 0.0, resp = 0.0, offs = 0.0;
        for (int k = tid; k < NBLK; k += NTHR) {
            float4 v = partials[k];
            neg += (double)v.x; cls += (double)v.y;
            resp += (double)v.z; offs += (double)v.w;
        }
        #pragma unroll
        for (int o = 32; o > 0; o >>= 1) {
            neg  += __shfl_down(neg,  o, 64);
            cls  += __shfl_down(cls,  o, 64);
            resp += __shfl_down(resp, o, 64);
            offs += __shfl_down(offs, o, 64);
        }
        __shared__ double sd[4][NTHR / 64];
        const int w = tid >> 6;
        if ((tid & 63) == 0) { sd[0][w] = neg; sd[1][w] = cls; sd[2][w] = resp; sd[3][w] = offs; }
        __syncthreads();
        if (tid == 0) {
            double N = 0, C = 0, R = 0, O = 0;
            #pragma unroll
            for (int k = 0; k < NTHR / 64; ++k) {
                N += sd[0][k]; C += sd[1][k]; R += sd[2][k]; O += sd[3][k];
            }
            out[0] = (float)(R / (double)BATCH);        // pObj   (L_OBJ = 1)
            out[1] = (float)(N / (double)BATCH * 0.5);  // nObj   (L_NOOBJ)
            out[2] = (float)(C / (double)BATCH);        // cls
            out[3] = (float)(O / (double)BATCH * 5.0);  // off    (L_COORD)
        }
    }
}

extern "C" void kernel_launch(void* const* d_in, const int* in_sizes, int n_in,
                              void* d_out, int out_size, void* d_ws, size_t ws_size,
                              hipStream_t stream) {
    const float* pred_cls   = (const float*)d_in[0];
    const float* pred_resp  = (const float*)d_in[1];
    const float* pred_box   = (const float*)d_in[2];
    const float* label_cls  = (const float*)d_in[3];
    const float* label_resp = (const float*)d_in[4];
    const float* label_box  = (const float*)d_in[5];

    float4* partials = (float4*)d_ws;
    float* out = (float*)d_out;

    void* args[] = { (void*)&pred_cls, (void*)&pred_resp, (void*)&pred_box,
                     (void*)&label_cls, (void*)&label_resp, (void*)&label_box,
                     (void*)&partials, (void*)&out };
    hipLaunchCooperativeKernel((const void*)yolo_onepass_kernel,
                               dim3(NBLK), dim3(NTHR), args, 0, stream);
}

// Round 5
// 18.106 us; speedup vs baseline: 7.7294x; 7.7294x over previous
//
#include <hip/hip_runtime.h>

#define BATCH 64
#define CLSN 80
#define BBOXN 2
#define HWN (56 * 56)
#define NCELLS (BATCH * HWN)   // 200704
#define NTHR 256
#define NBLK (NCELLS / NTHR)   // 784, exact

// ws layout: float4 partials[NBLK]  {neg, cls, resp, off}

__global__ void yolo_fused_kernel(const float* __restrict__ pred_cls,
                                  const float* __restrict__ pred_resp,
                                  const float* __restrict__ pred_box,
                                  const float* __restrict__ label_cls,
                                  const float* __restrict__ label_resp,
                                  const float* __restrict__ label_box,
                                  float4* __restrict__ partials) {
    const int tid = threadIdx.x;
    const int i = blockIdx.x * NTHR + tid;          // grid covers NCELLS exactly
    const int b = i / HWN;
    const int yx = i - b * HWN;
    const int rbase = b * (BBOXN * HWN) + yx;

    // coalesced: consecutive threads -> consecutive yx
    const float l0 = label_resp[rbase];
    const float l1 = label_resp[rbase + HWN];
    const float p0 = pred_resp[rbase];
    const float p1 = pred_resp[rbase + HWN];

    float negAcc = 0.0f, clsAcc = 0.0f, respAcc = 0.0f, offAcc = 0.0f;
    if (l0 < 1.0f) { float d = p0 - l0; negAcc += d * d; }
    if (l1 < 1.0f) { float d = p1 - l1; negAcc += d * d; }

    const bool sel = (l0 + l1) >= 0.5f;

    // ---- issue the scattered box loads EARLY; consume after the cls loop ----
    float t[8], p[8];
    if (sel) {
        const int bbase = b * (BBOXN * 4) * HWN + yx;
        #pragma unroll
        for (int k = 0; k < 8; ++k) {
            t[k] = label_box[bbase + k * HWN];
            p[k] = pred_box[bbase + k * HWN];
        }
    }

    // ---- classification loss: wave-cooperative, 4 selected cells per round ----
    // Each round issues all loads for up to 4 cells before any use; invalid
    // slots duplicate slot 0's address (same cache line -> no extra HBM).
    const int lane = tid & 63;
    const int ibase = i - lane;                     // wave's first cell index
    unsigned long long mask = __ballot(sel);
    while (mask) {
        int srcs[4];
        bool val[4];
        srcs[0] = (int)__builtin_ctzll(mask); val[0] = true;
        mask &= mask - 1;
        #pragma unroll
        for (int s = 1; s < 4; ++s) {
            val[s] = (mask != 0);
            srcs[s] = val[s] ? (int)__builtin_ctzll(mask) : srcs[0];
            mask = val[s] ? (mask & (mask - 1)) : mask;
        }
        int base0[4], base1[4];
        #pragma unroll
        for (int s = 0; s < 4; ++s) {
            const int ci = ibase + srcs[s];
            const int cb = ci / HWN;
            const int cyx = ci - cb * HWN;
            const int cbase = cb * (CLSN * HWN) + cyx;
            base0[s] = cbase + lane * HWN;          // classes 0..63
            base1[s] = cbase + (64 + lane) * HWN;   // classes 64..79 (lane<16)
        }
        float dp0[4], dl0[4], dp1[4], dl1[4];
        #pragma unroll
        for (int s = 0; s < 4; ++s) {
            dp0[s] = pred_cls[base0[s]];
            dl0[s] = label_cls[base0[s]];
        }
        if (lane < CLSN - 64) {
            #pragma unroll
            for (int s = 0; s < 4; ++s) {
                dp1[s] = pred_cls[base1[s]];
                dl1[s] = label_cls[base1[s]];
            }
        }
        #pragma unroll
        for (int s = 0; s < 4; ++s) {
            float d = dp0[s] - dl0[s];
            clsAcc += val[s] ? d * d : 0.0f;
        }
        if (lane < CLSN - 64) {
            #pragma unroll
            for (int s = 0; s < 4; ++s) {
                float d = dp1[s] - dl1[s];
                clsAcc += val[s] ? d * d : 0.0f;
            }
        }
    }

    // ---- box / response loss: consume the early-issued loads ----
    if (sel) {
        float iou[2];
        #pragma unroll
        for (int bx = 0; bx < 2; ++bx) {
            float tx1 = t[bx * 4 + 0] - t[bx * 4 + 2] * 0.5f;
            float ty1 = t[bx * 4 + 1] - t[bx * 4 + 3] * 0.5f;
            float tx2 = tx1 + t[bx * 4 + 2];
            float ty2 = ty1 + t[bx * 4 + 3];
            float px1 = p[bx * 4 + 0] - p[bx * 4 + 2] * 0.5f;
            float py1 = p[bx * 4 + 1] - p[bx * 4 + 3] * 0.5f;
            float px2 = px1 + p[bx * 4 + 2];
            float py2 = py1 + p[bx * 4 + 3];
            float ltx = fmaxf(tx1, px1), lty = fmaxf(ty1, py1);
            float rbx = fminf(tx2, px2), rby = fminf(ty2, py2);
            float w_ = fmaxf(rbx - ltx, 0.0f), h_ = fmaxf(rby - lty, 0.0f);
            float inter = w_ * h_;
            float a1 = (tx2 - tx1) * (ty2 - ty1);
            float a2 = (px2 - px1) * (py2 - py1);
            iou[bx] = inter / (a1 + a2 - inter + 0.0001f);
        }
        const int best = (iou[1] > iou[0]) ? 1 : 0;   // argmax, ties -> 0
        const float pr = best ? p1 : p0;              // pred_resp already loaded
        const float dr = pr - iou[best];
        respAcc = dr * dr;
        #pragma unroll
        for (int k = 0; k < 4; ++k) {
            float d2 = p[best * 4 + k] - t[best * 4 + k];
            offAcc += d2 * d2;
        }
    }

    // ---- block reduction, one float4 store per block ----
    #pragma unroll
    for (int o = 32; o > 0; o >>= 1) {
        negAcc  += __shfl_down(negAcc,  o, 64);
        clsAcc  += __shfl_down(clsAcc,  o, 64);
        respAcc += __shfl_down(respAcc, o, 64);
        offAcc  += __shfl_down(offAcc,  o, 64);
    }
    __shared__ float4 s[NTHR / 64];
    if ((tid & 63) == 0) s[tid >> 6] = make_float4(negAcc, clsAcc, respAcc, offAcc);
    __syncthreads();
    if (tid == 0) {
        float4 tt = s[0];
        #pragma unroll
        for (int w = 1; w < NTHR / 64; ++w) {
            tt.x += s[w].x; tt.y += s[w].y; tt.z += s[w].z; tt.w += s[w].w;
        }
        partials[blockIdx.x] = tt;
    }
}

__global__ void yolo_finalize_kernel(const float4* __restrict__ partials,
                                     float* __restrict__ out) {
    const int tid = threadIdx.x;
    double neg = 0.0, cls = 0.0, resp = 0.0, offs = 0.0;
    for (int k = tid; k < NBLK; k += NTHR) {
        float4 t = partials[k];
        neg += (double)t.x; cls += (double)t.y;
        resp += (double)t.z; offs += (double)t.w;
    }
    #pragma unroll
    for (int o = 32; o > 0; o >>= 1) {
        neg  += __shfl_down(neg,  o, 64);
        cls  += __shfl_down(cls,  o, 64);
        resp += __shfl_down(resp, o, 64);
        offs += __shfl_down(offs, o, 64);
    }
    __shared__ double s[4][NTHR / 64];
    const int w = tid >> 6;
    if ((tid & 63) == 0) { s[0][w] = neg; s[1][w] = cls; s[2][w] = resp; s[3][w] = offs; }
    __syncthreads();
    if (tid == 0) {
        double N = 0, C = 0, R = 0, O = 0;
        #pragma unroll
        for (int k = 0; k < NTHR / 64; ++k) {
            N += s[0][k]; C += s[1][k]; R += s[2][k]; O += s[3][k];
        }
        out[0] = (float)(R / (double)BATCH);        // pObj   (L_OBJ = 1)
        out[1] = (float)(N / (double)BATCH * 0.5);  // nObj   (L_NOOBJ)
        out[2] = (float)(C / (double)BATCH);        // cls
        out[3] = (float)(O / (double)BATCH * 5.0);  // off    (L_COORD)
    }
}

extern "C" void kernel_launch(void* const* d_in, const int* in_sizes, int n_in,
                              void* d_out, int out_size, void* d_ws, size_t ws_size,
                              hipStream_t stream) {
    const float* pred_cls   = (const float*)d_in[0];
    const float* pred_resp  = (const float*)d_in[1];
    const float* pred_box   = (const float*)d_in[2];
    const float* label_cls  = (const float*)d_in[3];
    const float* label_resp = (const float*)d_in[4];
    const float* label_box  = (const float*)d_in[5];

    float4* partials = (float4*)d_ws;
    float* out = (float*)d_out;

    yolo_fused_kernel<<<NBLK, NTHR, 0, stream>>>(
        pred_cls, pred_resp, pred_box, label_cls, label_resp, label_box, partials);

    yolo_finalize_kernel<<<1, NTHR, 0, stream>>>(partials, out);
}

// Round 6
// 15.233 us; speedup vs baseline: 9.1875x; 1.1886x over previous
//
#include <hip/hip_runtime.h>

#define BATCH 64
#define CLSN 80
#define BBOXN 2
#define HWN (56 * 56)
#define NCELLS (BATCH * HWN)   // 200704
#define NTHR 256
#define NBLK (NCELLS / NTHR)   // 784, exact

// ws layout: float4 partials[NBLK]  {neg, cls, resp, off}

__global__ void yolo_fused_kernel(const float* __restrict__ pred_cls,
                                  const float* __restrict__ pred_resp,
                                  const float* __restrict__ pred_box,
                                  const float* __restrict__ label_cls,
                                  const float* __restrict__ label_resp,
                                  const float* __restrict__ label_box,
                                  float4* __restrict__ partials) {
    __shared__ int s_cnt;
    __shared__ int s_list[128];          // cbase = b*CLSN*HWN + yx per selected cell

    const int tid = threadIdx.x;
    if (tid == 0) s_cnt = 0;

    const int i = blockIdx.x * NTHR + tid;          // grid covers NCELLS exactly
    const int b = i / HWN;
    const int yx = i - b * HWN;
    const int rbase = b * (BBOXN * HWN) + yx;

    // coalesced: consecutive threads -> consecutive yx
    const float l0 = label_resp[rbase];
    const float l1 = label_resp[rbase + HWN];
    const float p0 = pred_resp[rbase];
    const float p1 = pred_resp[rbase + HWN];

    float negAcc = 0.0f, clsAcc = 0.0f, respAcc = 0.0f, offAcc = 0.0f;
    if (l0 < 1.0f) { float d = p0 - l0; negAcc += d * d; }
    if (l1 < 1.0f) { float d = p1 - l1; negAcc += d * d; }

    const bool sel = (l0 + l1) >= 0.5f;

    // ---- issue the scattered box loads EARLY; consume after the cls phase ----
    float t[8], p[8];
    if (sel) {
        const int bbase = b * (BBOXN * 4) * HWN + yx;
        #pragma unroll
        for (int k = 0; k < 8; ++k) {
            t[k] = label_box[bbase + k * HWN];
            p[k] = pred_box[bbase + k * HWN];
        }
    }

    __syncthreads();                     // s_cnt = 0 visible to all
    if (sel) {
        int slot = atomicAdd(&s_cnt, 1); // LDS atomic, ~2.6 per block
        s_list[slot] = b * (CLSN * HWN) + yx;
    }
    __syncthreads();
    const int nsel = s_cnt;              // block-uniform

    // ---- classification loss: block-cooperative, 3 cells x 80 classes/round,
    //      2 rounds unrolled so up to 4 independent loads are in flight ----
    const int cslot = tid / CLSN;        // 0..3 (3 full slots, tid<240)
    const int ccls  = tid - cslot * CLSN;
    const bool lane_ok = (tid < 3 * CLSN);
    for (int r = 0; r < nsel; r += 6) {
        const int sA = r + cslot;
        const int sB = r + cslot + 3;
        const bool aA = lane_ok && (sA < nsel);
        const bool aB = lane_ok && (sB < nsel);
        float pA = 0.0f, lA = 0.0f, pB = 0.0f, lB = 0.0f;
        if (aA) {
            const int ofs = s_list[sA] + ccls * HWN;
            pA = pred_cls[ofs]; lA = label_cls[ofs];
        }
        if (aB) {
            const int ofs = s_list[sB] + ccls * HWN;
            pB = pred_cls[ofs]; lB = label_cls[ofs];
        }
        if (aA) { float d = pA - lA; clsAcc += d * d; }
        if (aB) { float d = pB - lB; clsAcc += d * d; }
    }

    // ---- box / response loss: consume the early-issued loads ----
    if (sel) {
        float iou[2];
        #pragma unroll
        for (int bx = 0; bx < 2; ++bx) {
            float tx1 = t[bx * 4 + 0] - t[bx * 4 + 2] * 0.5f;
            float ty1 = t[bx * 4 + 1] - t[bx * 4 + 3] * 0.5f;
            float tx2 = tx1 + t[bx * 4 + 2];
            float ty2 = ty1 + t[bx * 4 + 3];
            float px1 = p[bx * 4 + 0] - p[bx * 4 + 2] * 0.5f;
            float py1 = p[bx * 4 + 1] - p[bx * 4 + 3] * 0.5f;
            float px2 = px1 + p[bx * 4 + 2];
            float py2 = py1 + p[bx * 4 + 3];
            float ltx = fmaxf(tx1, px1), lty = fmaxf(ty1, py1);
            float rbx = fminf(tx2, px2), rby = fminf(ty2, py2);
            float w_ = fmaxf(rbx - ltx, 0.0f), h_ = fmaxf(rby - lty, 0.0f);
            float inter = w_ * h_;
            float a1 = (tx2 - tx1) * (ty2 - ty1);
            float a2 = (px2 - px1) * (py2 - py1);
            iou[bx] = inter / (a1 + a2 - inter + 0.0001f);
        }
        const int best = (iou[1] > iou[0]) ? 1 : 0;   // argmax, ties -> 0
        const float pr = best ? p1 : p0;              // pred_resp already loaded
        const float dr = pr - iou[best];
        respAcc = dr * dr;
        #pragma unroll
        for (int k = 0; k < 4; ++k) {
            float d2 = p[best * 4 + k] - t[best * 4 + k];
            offAcc += d2 * d2;
        }
    }

    // ---- block reduction, one float4 store per block ----
    #pragma unroll
    for (int o = 32; o > 0; o >>= 1) {
        negAcc  += __shfl_down(negAcc,  o, 64);
        clsAcc  += __shfl_down(clsAcc,  o, 64);
        respAcc += __shfl_down(respAcc, o, 64);
        offAcc  += __shfl_down(offAcc,  o, 64);
    }
    __shared__ float4 s[NTHR / 64];
    if ((tid & 63) == 0) s[tid >> 6] = make_float4(negAcc, clsAcc, respAcc, offAcc);
    __syncthreads();
    if (tid == 0) {
        float4 tt = s[0];
        #pragma unroll
        for (int w = 1; w < NTHR / 64; ++w) {
            tt.x += s[w].x; tt.y += s[w].y; tt.z += s[w].z; tt.w += s[w].w;
        }
        partials[blockIdx.x] = tt;
    }
}

__global__ void yolo_finalize_kernel(const float4* __restrict__ partials,
                                     float* __restrict__ out) {
    const int tid = threadIdx.x;
    double neg = 0.0, cls = 0.0, resp = 0.0, offs = 0.0;
    for (int k = tid; k < NBLK; k += NTHR) {
        float4 t = partials[k];
        neg += (double)t.x; cls += (double)t.y;
        resp += (double)t.z; offs += (double)t.w;
    }
    #pragma unroll
    for (int o = 32; o > 0; o >>= 1) {
        neg  += __shfl_down(neg,  o, 64);
        cls  += __shfl_down(cls,  o, 64);
        resp += __shfl_down(resp, o, 64);
        offs += __shfl_down(offs, o, 64);
    }
    __shared__ double s[4][NTHR / 64];
    const int w = tid >> 6;
    if ((tid & 63) == 0) { s[0][w] = neg; s[1][w] = cls; s[2][w] = resp; s[3][w] = offs; }
    __syncthreads();
    if (tid == 0) {
        double N = 0, C = 0, R = 0, O = 0;
        #pragma unroll
        for (int k = 0; k < NTHR / 64; ++k) {
            N += s[0][k]; C += s[1][k]; R += s[2][k]; O += s[3][k];
        }
        out[0] = (float)(R / (double)BATCH);        // pObj   (L_OBJ = 1)
        out[1] = (float)(N / (double)BATCH * 0.5);  // nObj   (L_NOOBJ)
        out[2] = (float)(C / (double)BATCH);        // cls
        out[3] = (float)(O / (double)BATCH * 5.0);  // off    (L_COORD)
    }
}

extern "C" void kernel_launch(void* const* d_in, const int* in_sizes, int n_in,
                              void* d_out, int out_size, void* d_ws, size_t ws_size,
                              hipStream_t stream) {
    const float* pred_cls   = (const float*)d_in[0];
    const float* pred_resp  = (const float*)d_in[1];
    const float* pred_box   = (const float*)d_in[2];
    const float* label_cls  = (const float*)d_in[3];
    const float* label_resp = (const float*)d_in[4];
    const float* label_box  = (const float*)d_in[5];

    float4* partials = (float4*)d_ws;
    float* out = (float*)d_out;

    yolo_fused_kernel<<<NBLK, NTHR, 0, stream>>>(
        pred_cls, pred_resp, pred_box, label_cls, label_resp, label_box, partials);

    yolo_finalize_kernel<<<1, NTHR, 0, stream>>>(partials, out);
}